// Round 9
// baseline (444.989 us; speedup 1.0000x reference)
//
#include <hip/hip_runtime.h>

#define N_NODES 100000
#define N_EDGES 1600000
#define N_GRAPHS 64

// Counting-sort tiling: 32 edge chunks x 8 node ranges. Build is atomic-free
// (R5/R6). R8 lesson: random-gather kernels are bound by per-XCD L2 residency
// of the gathered buffer (4 MiB). p at stride 10 = 4.0 MB fits; stride 12 =
// 4.8 MB thrashed L2 and tripled layer3 (43->117us). So: p stays stride 10,
// layer3 uses 10 scalar lanes/node (R7-proven <43us). xs (3.2MB) fits; h16
// (6.4MB) does not -- layer2 is the expected top kernel now.
#define NCHUNK 32
#define CHUNK_E (N_EDGES / NCHUNK)   // 50000
#define NRANGE 8
#define RANGE_N (N_NODES / NRANGE)   // 12500
#define SCAN_BLK 256

// ---------------- fused histogram: dst -> u16 partials, src -> u8 partials ----------
__global__ void hist_kernel(const int* __restrict__ dst, const int* __restrict__ src,
                            unsigned short* __restrict__ pcnt,
                            unsigned int* __restrict__ pcnt8) {
    __shared__ int h[RANGE_N];                   // 50000 B
    __shared__ unsigned int h8[RANGE_N / 4];     // 12500 B (packed u8 x4)
    int c = blockIdx.x >> 3;        // chunk
    int r = blockIdx.x & 7;         // node range
    for (int k = threadIdx.x; k < RANGE_N; k += blockDim.x) h[k] = 0;
    for (int k = threadIdx.x; k < RANGE_N / 4; k += blockDim.x) h8[k] = 0;
    __syncthreads();
    int lo = r * RANGE_N;
    const int4* d4 = (const int4*)(dst + c * CHUNK_E);
    const int4* s4 = (const int4*)(src + c * CHUNK_E);
    for (int k = threadIdx.x; k < CHUNK_E / 4; k += blockDim.x) {
        int4 v = d4[k];
        int d0 = v.x - lo, d1 = v.y - lo, d2 = v.z - lo, d3 = v.w - lo;
        if ((unsigned)d0 < RANGE_N) atomicAdd(&h[d0], 1);
        if ((unsigned)d1 < RANGE_N) atomicAdd(&h[d1], 1);
        if ((unsigned)d2 < RANGE_N) atomicAdd(&h[d2], 1);
        if ((unsigned)d3 < RANGE_N) atomicAdd(&h[d3], 1);
        int4 s = s4[k];
        int s0 = s.x - lo, s1 = s.y - lo, s2 = s.z - lo, s3 = s.w - lo;
        if ((unsigned)s0 < RANGE_N) atomicAdd(&h8[s0 >> 2], 1u << (8 * (s0 & 3)));
        if ((unsigned)s1 < RANGE_N) atomicAdd(&h8[s1 >> 2], 1u << (8 * (s1 & 3)));
        if ((unsigned)s2 < RANGE_N) atomicAdd(&h8[s2 >> 2], 1u << (8 * (s2 & 3)));
        if ((unsigned)s3 < RANGE_N) atomicAdd(&h8[s3 >> 2], 1u << (8 * (s3 & 3)));
    }
    __syncthreads();
    unsigned short* p = pcnt + (size_t)c * N_NODES + lo;
    for (int k = threadIdx.x; k < RANGE_N; k += blockDim.x) p[k] = (unsigned short)h[k];
    unsigned int* p8 = pcnt8 + ((size_t)c * N_NODES + lo) / 4;
    for (int k = threadIdx.x; k < RANGE_N / 4; k += blockDim.x) p8[k] = h8[k];
}

// ------- per-node exclusive prefix over chunks + block partial sum (+ zero gsum/ticket) ----
__global__ void chunkscanA_kernel(unsigned short* __restrict__ pcnt, int* __restrict__ cnt_in,
                                  float* __restrict__ inv_in, int* __restrict__ partials,
                                  float* __restrict__ gz, int* __restrict__ ticket, int n) {
    if (blockIdx.x == 0) {
        for (int k = threadIdx.x; k < N_GRAPHS * 10 + N_GRAPHS; k += SCAN_BLK) gz[k] = 0.0f;
        if (threadIdx.x == 0) *ticket = 0;
    }
    __shared__ int red[SCAN_BLK];
    int i = blockIdx.x * SCAN_BLK + threadIdx.x;
    int s = 0;
    if (i < n) {
#pragma unroll
        for (int c = 0; c < NCHUNK; c++) {
            size_t off = (size_t)c * N_NODES + i;
            int v = pcnt[off];
            pcnt[off] = (unsigned short)s;   // chunk-exclusive prefix
            s += v;
        }
        cnt_in[i] = s;
        inv_in[i] = 1.0f / sqrtf(fmaxf((float)s, 1.0f));
    }
    red[threadIdx.x] = s;
    __syncthreads();
    for (int off = SCAN_BLK / 2; off > 0; off >>= 1) {
        if (threadIdx.x < off) red[threadIdx.x] += red[threadIdx.x + off];
        __syncthreads();
    }
    if (threadIdx.x == 0) partials[blockIdx.x] = red[0];
}

// ---- scanC: self-computed partials prefix (replaces scanB) + local exclusive scan ----
__global__ void scanC_kernel(const int* __restrict__ deg, const int* __restrict__ partials,
                             int* __restrict__ row_ptr, int n) {
    __shared__ int red[SCAN_BLK];
    __shared__ int s[SCAN_BLK];
    int acc = 0;
    for (int k = threadIdx.x; k < blockIdx.x; k += SCAN_BLK) acc += partials[k];
    red[threadIdx.x] = acc;
    __syncthreads();
    for (int off = SCAN_BLK / 2; off > 0; off >>= 1) {
        if (threadIdx.x < off) red[threadIdx.x] += red[threadIdx.x + off];
        __syncthreads();
    }
    int i = blockIdx.x * SCAN_BLK + threadIdx.x;
    int v = (i < n) ? deg[i] : 0;
    s[threadIdx.x] = v;
    __syncthreads();
    for (int off = 1; off < SCAN_BLK; off <<= 1) {
        int t = (threadIdx.x >= off) ? s[threadIdx.x - off] : 0;
        __syncthreads();
        s[threadIdx.x] += t;
        __syncthreads();
    }
    if (i < n) row_ptr[i] = red[0] + s[threadIdx.x] - v;
}

// ---- pass B: placement via LDS cursors (1 random store/edge) + outdeg/prescale tail ----
__global__ void place_kernel(const int* __restrict__ src, const int* __restrict__ dst,
                             const unsigned short* __restrict__ pcnt,
                             const int* __restrict__ row_ptr, int* __restrict__ csr_src,
                             const unsigned char* __restrict__ pcnt8,
                             const float* __restrict__ x,
                             float* __restrict__ inv_out, float* __restrict__ xs) {
    __shared__ int cur[RANGE_N];
    int c = blockIdx.x >> 3;
    int r = blockIdx.x & 7;
    int lo = r * RANGE_N;
    const unsigned short* p = pcnt + (size_t)c * N_NODES + lo;
    for (int k = threadIdx.x; k < RANGE_N; k += blockDim.x)
        cur[k] = row_ptr[lo + k] + (int)p[k];   // absolute base cursor
    __syncthreads();
    const int4* d4 = (const int4*)(dst + c * CHUNK_E);
    const int4* s4 = (const int4*)(src + c * CHUNK_E);
    for (int k = threadIdx.x; k < CHUNK_E / 4; k += blockDim.x) {
        int4 dv = d4[k];
        int d0 = dv.x - lo, d1 = dv.y - lo, d2 = dv.z - lo, d3 = dv.w - lo;
        bool n0 = (unsigned)d0 < RANGE_N, n1 = (unsigned)d1 < RANGE_N;
        bool n2 = (unsigned)d2 < RANGE_N, n3 = (unsigned)d3 < RANGE_N;
        if (n0 | n1 | n2 | n3) {   // skip src fetch when whole quad out of range
            int4 sv = s4[k];
            if (n0) csr_src[atomicAdd(&cur[d0], 1)] = sv.x;
            if (n1) csr_src[atomicAdd(&cur[d1], 1)] = sv.y;
            if (n2) csr_src[atomicAdd(&cur[d2], 1)] = sv.z;
            if (n3) csr_src[atomicAdd(&cur[d3], 1)] = sv.w;
        }
    }
    // ---- tail: out-degree sum + inv_out + prescale (depends only on hist's pcnt8) ----
    int i = blockIdx.x * blockDim.x + threadIdx.x;
    if (i < N_NODES) {
        int sd = 0;
#pragma unroll
        for (int cc = 0; cc < NCHUNK; cc++) sd += pcnt8[(size_t)cc * N_NODES + i];
        float io = 1.0f / sqrtf(fmaxf((float)sd, 1.0f));
        inv_out[i] = io;
        const float4* x4 = (const float4*)x;
        float4 a = x4[i * 2], b = x4[i * 2 + 1];
        a.x *= io; a.y *= io; a.z *= io; a.w *= io;
        b.x *= io; b.y *= io; b.z *= io; b.w *= io;
        float4* xs4 = (float4*)xs;
        xs4[i * 2] = a;
        xs4[i * 2 + 1] = b;
    }
}

// ---------------- layer 1 fused: gather d=8 (float4 x2 lanes) + @W1+b1, relu, *inv_out ----
__global__ __launch_bounds__(256) void
layer1_kernel(const float* __restrict__ xs, const int* __restrict__ row_ptr,
              const int* __restrict__ cnt_in, const int* __restrict__ csr_src,
              const float* __restrict__ inv_in, const float* __restrict__ inv_out,
              const float* __restrict__ W1, const float* __restrict__ b1,
              float* __restrict__ hout) {
    __shared__ float sW[8 * 16];
    __shared__ float sb[16];
    __shared__ float tile[128 * 8];
    if (threadIdx.x < 128) sW[threadIdx.x] = W1[threadIdx.x];
    if (threadIdx.x < 16) sb[threadIdx.x] = b1[threadIdx.x];
    int ii = threadIdx.x >> 1, f = threadIdx.x & 1;   // 2 lanes/node, float4 each
    int i = blockIdx.x * 128 + ii;
    const float4* xs4 = (const float4*)xs;
    float4 s = {0.f, 0.f, 0.f, 0.f};
    if (i < N_NODES) {
        int start = row_ptr[i], deg = cnt_in[i];
        int k = 0;
        for (; k + 7 < deg; k += 8) {   // 8 float4 loads in flight
            int e0 = csr_src[start + k],     e1 = csr_src[start + k + 1];
            int e2 = csr_src[start + k + 2], e3 = csr_src[start + k + 3];
            int e4 = csr_src[start + k + 4], e5 = csr_src[start + k + 5];
            int e6 = csr_src[start + k + 6], e7 = csr_src[start + k + 7];
            float4 v0 = xs4[e0 * 2 + f], v1 = xs4[e1 * 2 + f];
            float4 v2 = xs4[e2 * 2 + f], v3 = xs4[e3 * 2 + f];
            float4 v4 = xs4[e4 * 2 + f], v5 = xs4[e5 * 2 + f];
            float4 v6 = xs4[e6 * 2 + f], v7 = xs4[e7 * 2 + f];
            s.x += v0.x + v1.x + v2.x + v3.x + v4.x + v5.x + v6.x + v7.x;
            s.y += v0.y + v1.y + v2.y + v3.y + v4.y + v5.y + v6.y + v7.y;
            s.z += v0.z + v1.z + v2.z + v3.z + v4.z + v5.z + v6.z + v7.z;
            s.w += v0.w + v1.w + v2.w + v3.w + v4.w + v5.w + v6.w + v7.w;
        }
        for (; k < deg; k++) {
            float4 v = xs4[csr_src[start + k] * 2 + f];
            s.x += v.x; s.y += v.y; s.z += v.z; s.w += v.w;
        }
        float inv = inv_in[i];
        s.x *= inv; s.y *= inv; s.z *= inv; s.w *= inv;
    }
    ((float4*)tile)[ii * 2 + f] = s;
    __syncthreads();
#pragma unroll
    for (int rep = 0; rep < 8; rep++) {   // 128 nodes x 16 outputs
        int idx = threadIdx.x + rep * 256;
        int i2 = idx >> 4, j = idx & 15;
        int gi = blockIdx.x * 128 + i2;
        if (gi < N_NODES) {
            float o = sb[j];
#pragma unroll
            for (int k2 = 0; k2 < 8; k2++) o += tile[i2 * 8 + k2] * sW[k2 * 16 + j];
            hout[gi * 16 + j] = fmaxf(o, 0.0f) * inv_out[gi];
        }
    }
}

// ------- layer 2 fused: gather d=16 (float4 x4 lanes) + relu((.)@W2+b2)@W3, *inv_out ----
// Output stride 10 (p buffer = 4.0 MB: fits per-XCD L2 -- R8 lesson).
__global__ __launch_bounds__(256) void
layer2_kernel(const float* __restrict__ h, const int* __restrict__ row_ptr,
              const int* __restrict__ cnt_in, const int* __restrict__ csr_src,
              const float* __restrict__ inv_in, const float* __restrict__ inv_out,
              const float* __restrict__ W2, const float* __restrict__ b2,
              const float* __restrict__ W3, float* __restrict__ pout) {
    __shared__ float sW2[16 * 32];
    __shared__ float sb2[32];
    __shared__ float sW3[32 * 10];
    __shared__ float tile[64 * 16];
    __shared__ float otile[64 * 33];   // +1 pad: phase3 reads stride-32 across nodes
    for (int k = threadIdx.x; k < 512; k += 256) sW2[k] = W2[k];
    if (threadIdx.x < 32) sb2[threadIdx.x] = b2[threadIdx.x];
    for (int k = threadIdx.x; k < 320; k += 256) sW3[k] = W3[k];
    int ii = threadIdx.x >> 2, f = threadIdx.x & 3;   // 4 lanes/node, float4 each
    int i = blockIdx.x * 64 + ii;
    const float4* h4 = (const float4*)h;
    float4 s = {0.f, 0.f, 0.f, 0.f};
    if (i < N_NODES) {
        int start = row_ptr[i], deg = cnt_in[i];
        int k = 0;
        for (; k + 7 < deg; k += 8) {
            int e0 = csr_src[start + k],     e1 = csr_src[start + k + 1];
            int e2 = csr_src[start + k + 2], e3 = csr_src[start + k + 3];
            int e4 = csr_src[start + k + 4], e5 = csr_src[start + k + 5];
            int e6 = csr_src[start + k + 6], e7 = csr_src[start + k + 7];
            float4 v0 = h4[e0 * 4 + f], v1 = h4[e1 * 4 + f];
            float4 v2 = h4[e2 * 4 + f], v3 = h4[e3 * 4 + f];
            float4 v4 = h4[e4 * 4 + f], v5 = h4[e5 * 4 + f];
            float4 v6 = h4[e6 * 4 + f], v7 = h4[e7 * 4 + f];
            s.x += v0.x + v1.x + v2.x + v3.x + v4.x + v5.x + v6.x + v7.x;
            s.y += v0.y + v1.y + v2.y + v3.y + v4.y + v5.y + v6.y + v7.y;
            s.z += v0.z + v1.z + v2.z + v3.z + v4.z + v5.z + v6.z + v7.z;
            s.w += v0.w + v1.w + v2.w + v3.w + v4.w + v5.w + v6.w + v7.w;
        }
        for (; k < deg; k++) {
            float4 v = h4[csr_src[start + k] * 4 + f];
            s.x += v.x; s.y += v.y; s.z += v.z; s.w += v.w;
        }
        float inv = inv_in[i];
        s.x *= inv; s.y *= inv; s.z *= inv; s.w *= inv;
    }
    ((float4*)tile)[ii * 4 + f] = s;
    __syncthreads();
#pragma unroll
    for (int rep = 0; rep < 8; rep++) {   // 64 nodes x 32 hidden
        int idx = threadIdx.x + rep * 256;
        int i2 = idx >> 5, kk = idx & 31;
        if (blockIdx.x * 64 + i2 < N_NODES) {
            float o = sb2[kk];
#pragma unroll
            for (int m = 0; m < 16; m++) o += tile[i2 * 16 + m] * sW2[m * 32 + kk];
            otile[i2 * 33 + kk] = fmaxf(o, 0.0f);
        }
    }
    __syncthreads();
#pragma unroll
    for (int rep = 0; rep < 3; rep++) {   // 64 nodes x 10 outputs
        int idx = threadIdx.x + rep * 256;
        if (idx < 640) {
            int i2 = idx / 10, j = idx - i2 * 10;
            int gi = blockIdx.x * 64 + i2;
            if (gi < N_NODES) {
                float pv = 0.0f;
#pragma unroll
                for (int k2 = 0; k2 < 32; k2++) pv += otile[i2 * 33 + k2] * sW3[k2 * 10 + j];
                pout[gi * 10 + j] = pv * inv_out[gi];
            }
        }
    }
}

// ---- layer 3 fused (R7-proven): gather d=10 scalar + *inv_in + b3 + LDS graph mean
// ---- + last-block finalize (ticket; reads back via atomicAdd(p,0) for XCD coherence)
__global__ __launch_bounds__(1024) void
layer3_kernel(const float* __restrict__ p, const int* __restrict__ row_ptr,
              const int* __restrict__ cnt_in, const int* __restrict__ csr_src,
              const float* __restrict__ inv_in, const float* __restrict__ b3,
              const int* __restrict__ gid, float* __restrict__ gsum,
              float* __restrict__ gcnt, int* __restrict__ ticket,
              float* __restrict__ out, int n10) {
    __shared__ float sb3[10];
    __shared__ float lsum[N_GRAPHS * 10];
    __shared__ float lcnt[N_GRAPHS];
    __shared__ int is_last;
    if (threadIdx.x < 10) sb3[threadIdx.x] = b3[threadIdx.x];
    for (int k = threadIdx.x; k < N_GRAPHS * 10; k += 1024) lsum[k] = 0.0f;
    if (threadIdx.x < N_GRAPHS) lcnt[threadIdx.x] = 0.0f;
    __syncthreads();
    int t = blockIdx.x * 1024 + threadIdx.x;
    if (t < n10) {
        int i = t / 10, f = t - i * 10;
        int start = row_ptr[i], deg = cnt_in[i];
        float s = 0.0f;
        int k = 0;
        for (; k + 7 < deg; k += 8) {
            int e0 = csr_src[start + k],     e1 = csr_src[start + k + 1];
            int e2 = csr_src[start + k + 2], e3 = csr_src[start + k + 3];
            int e4 = csr_src[start + k + 4], e5 = csr_src[start + k + 5];
            int e6 = csr_src[start + k + 6], e7 = csr_src[start + k + 7];
            s += p[e0 * 10 + f]; s += p[e1 * 10 + f]; s += p[e2 * 10 + f]; s += p[e3 * 10 + f];
            s += p[e4 * 10 + f]; s += p[e5 * 10 + f]; s += p[e6 * 10 + f]; s += p[e7 * 10 + f];
        }
        for (; k < deg; k++) s += p[csr_src[start + k] * 10 + f];
        float o = s * inv_in[i] + sb3[f];
        int g = gid[i];
        atomicAdd(&lsum[g * 10 + f], o);
        if (f == 0) atomicAdd(&lcnt[g], 1.0f);
    }
    __syncthreads();
    for (int k = threadIdx.x; k < N_GRAPHS * 10; k += 1024) {
        float v = lsum[k];
        if (v != 0.0f) atomicAdd(&gsum[k], v);
    }
    if (threadIdx.x < N_GRAPHS) {
        float v = lcnt[threadIdx.x];
        if (v != 0.0f) atomicAdd(&gcnt[threadIdx.x], v);
    }
    __threadfence();
    if (threadIdx.x == 0) is_last = (atomicAdd(ticket, 1) == (int)gridDim.x - 1);
    __syncthreads();
    if (is_last && threadIdx.x < N_GRAPHS * 10) {
        float sv = atomicAdd(&gsum[threadIdx.x], 0.0f);       // device-coherent read
        float cv = atomicAdd(&gcnt[threadIdx.x / 10], 0.0f);
        out[threadIdx.x] = sv / fmaxf(cv, 1.0f);
    }
}

extern "C" void kernel_launch(void* const* d_in, const int* in_sizes, int n_in,
                              void* d_out, int out_size, void* d_ws, size_t ws_size,
                              hipStream_t stream) {
    const float* n_feat = (const float*)d_in[0];  // [N,8]
    const int*   src    = (const int*)d_in[1];    // [E]
    const int*   dst    = (const int*)d_in[2];    // [E]
    const int*   gid    = (const int*)d_in[3];    // [N]
    const float* W1     = (const float*)d_in[4];  // [8,16]
    const float* b1     = (const float*)d_in[5];
    const float* W2     = (const float*)d_in[6];  // [16,32]
    const float* b2     = (const float*)d_in[7];
    const float* W3     = (const float*)d_in[8];  // [32,10]
    const float* b3     = (const float*)d_in[9];
    float* out = (float*)d_out;

    // ---- workspace layout (~30.4 MB; >=32.4 MB proven available in R4) ----
    float* ws      = (float*)d_ws;
    float* inv_out = ws;
    float* inv_in  = ws + N_NODES;
    float* bufA    = ws + 2 * N_NODES;    // h16 (16N)
    float* bufB    = ws + 18 * N_NODES;   // xs (8N), later p10 (10N)
    float* gsum    = ws + 34 * N_NODES;
    float* gcnt    = gsum + N_GRAPHS * 10;
    int* ibase     = (int*)(gcnt + N_GRAPHS);
    int* cnt_in    = ibase;
    int* row_ptr   = ibase + N_NODES;
    int* spart     = ibase + 2 * N_NODES;
    int* ticket    = ibase + 2 * N_NODES + 512;
    int* csr_src   = ibase + 2 * N_NODES + 1024;
    unsigned short* pcnt = (unsigned short*)(csr_src + N_EDGES);
    unsigned int* pcnt8 = (unsigned int*)(pcnt + (size_t)NCHUNK * N_NODES);

    const int BIGBLK = 1024;
    const int NPARTS = (N_NODES + SCAN_BLK - 1) / SCAN_BLK;  // 391
    const int TGRID = NCHUNK * NRANGE;                        // 256

    // ---- atomic-free graph build (4 dispatches) ----
    hist_kernel<<<TGRID, BIGBLK, 0, stream>>>(dst, src, pcnt, pcnt8);
    chunkscanA_kernel<<<NPARTS, SCAN_BLK, 0, stream>>>(pcnt, cnt_in, inv_in, spart,
                                                       gsum, ticket, N_NODES);
    scanC_kernel<<<NPARTS, SCAN_BLK, 0, stream>>>(cnt_in, spart, row_ptr, N_NODES);
    place_kernel<<<TGRID, BIGBLK, 0, stream>>>(src, dst, pcnt, row_ptr, csr_src,
                                               (const unsigned char*)pcnt8, n_feat,
                                               inv_out, bufB);

    // ---- three fused layers (3 dispatches; layer3 includes finalize) ----
    layer1_kernel<<<(N_NODES + 127) / 128, 256, 0, stream>>>(
        bufB, row_ptr, cnt_in, csr_src, inv_in, inv_out, W1, b1, bufA);
    layer2_kernel<<<(N_NODES + 63) / 64, 256, 0, stream>>>(
        bufA, row_ptr, cnt_in, csr_src, inv_in, inv_out, W2, b2, W3, bufB);
    layer3_kernel<<<(N_NODES * 10 + BIGBLK - 1) / BIGBLK, BIGBLK, 0, stream>>>(
        bufB, row_ptr, cnt_in, csr_src, inv_in, b3, gid, gsum, gcnt, ticket, out,
        N_NODES * 10);
}

// Round 10
// 206.561 us; speedup vs baseline: 2.1543x; 2.1543x over previous
//
#include <hip/hip_runtime.h>

#define N_NODES 100000
#define N_EDGES 1600000
#define N_GRAPHS 64

// Counting-sort tiling: 32 edge chunks x 8 node ranges. Build is atomic-free
// (R5/R6). R9 lesson (confirmed by R8/R9 wave-count scaling): __threadfence()
// in a fat-grid kernel costs ~10us per 1000 waves on gfx950 (device-scope
// release = L2 writeback + drain, serialized) -- NEVER fuse a grid-wide
// finalize via ticket+fence. Separate 2us finalize dispatch is the right
// price. Layer3 gather itself is L2-resident (p stride 10 = 4.0MB/XCD-L2).
#define NCHUNK 32
#define CHUNK_E (N_EDGES / NCHUNK)   // 50000
#define NRANGE 8
#define RANGE_N (N_NODES / NRANGE)   // 12500
#define SCAN_BLK 256

// ---------------- fused histogram: dst -> u16 partials, src -> u8 partials ----------
__global__ void hist_kernel(const int* __restrict__ dst, const int* __restrict__ src,
                            unsigned short* __restrict__ pcnt,
                            unsigned int* __restrict__ pcnt8) {
    __shared__ int h[RANGE_N];                   // 50000 B
    __shared__ unsigned int h8[RANGE_N / 4];     // 12500 B (packed u8 x4)
    int c = blockIdx.x >> 3;        // chunk
    int r = blockIdx.x & 7;         // node range
    for (int k = threadIdx.x; k < RANGE_N; k += blockDim.x) h[k] = 0;
    for (int k = threadIdx.x; k < RANGE_N / 4; k += blockDim.x) h8[k] = 0;
    __syncthreads();
    int lo = r * RANGE_N;
    const int4* d4 = (const int4*)(dst + c * CHUNK_E);
    const int4* s4 = (const int4*)(src + c * CHUNK_E);
    for (int k = threadIdx.x; k < CHUNK_E / 4; k += blockDim.x) {
        int4 v = d4[k];
        int d0 = v.x - lo, d1 = v.y - lo, d2 = v.z - lo, d3 = v.w - lo;
        if ((unsigned)d0 < RANGE_N) atomicAdd(&h[d0], 1);
        if ((unsigned)d1 < RANGE_N) atomicAdd(&h[d1], 1);
        if ((unsigned)d2 < RANGE_N) atomicAdd(&h[d2], 1);
        if ((unsigned)d3 < RANGE_N) atomicAdd(&h[d3], 1);
        int4 s = s4[k];
        int s0 = s.x - lo, s1 = s.y - lo, s2 = s.z - lo, s3 = s.w - lo;
        if ((unsigned)s0 < RANGE_N) atomicAdd(&h8[s0 >> 2], 1u << (8 * (s0 & 3)));
        if ((unsigned)s1 < RANGE_N) atomicAdd(&h8[s1 >> 2], 1u << (8 * (s1 & 3)));
        if ((unsigned)s2 < RANGE_N) atomicAdd(&h8[s2 >> 2], 1u << (8 * (s2 & 3)));
        if ((unsigned)s3 < RANGE_N) atomicAdd(&h8[s3 >> 2], 1u << (8 * (s3 & 3)));
    }
    __syncthreads();
    unsigned short* p = pcnt + (size_t)c * N_NODES + lo;
    for (int k = threadIdx.x; k < RANGE_N; k += blockDim.x) p[k] = (unsigned short)h[k];
    unsigned int* p8 = pcnt8 + ((size_t)c * N_NODES + lo) / 4;
    for (int k = threadIdx.x; k < RANGE_N / 4; k += blockDim.x) p8[k] = h8[k];
}

// ------- per-node exclusive prefix over chunks + block partial sum (+ zero gsum) -------
__global__ void chunkscanA_kernel(unsigned short* __restrict__ pcnt, int* __restrict__ cnt_in,
                                  float* __restrict__ inv_in, int* __restrict__ partials,
                                  float* __restrict__ gz, int n) {
    if (blockIdx.x == 0) {
        for (int k = threadIdx.x; k < N_GRAPHS * 10 + N_GRAPHS; k += SCAN_BLK) gz[k] = 0.0f;
    }
    __shared__ int red[SCAN_BLK];
    int i = blockIdx.x * SCAN_BLK + threadIdx.x;
    int s = 0;
    if (i < n) {
#pragma unroll
        for (int c = 0; c < NCHUNK; c++) {
            size_t off = (size_t)c * N_NODES + i;
            int v = pcnt[off];
            pcnt[off] = (unsigned short)s;   // chunk-exclusive prefix
            s += v;
        }
        cnt_in[i] = s;
        inv_in[i] = 1.0f / sqrtf(fmaxf((float)s, 1.0f));
    }
    red[threadIdx.x] = s;
    __syncthreads();
    for (int off = SCAN_BLK / 2; off > 0; off >>= 1) {
        if (threadIdx.x < off) red[threadIdx.x] += red[threadIdx.x + off];
        __syncthreads();
    }
    if (threadIdx.x == 0) partials[blockIdx.x] = red[0];
}

// ---- scanC: self-computed partials prefix + local exclusive scan ----
__global__ void scanC_kernel(const int* __restrict__ deg, const int* __restrict__ partials,
                             int* __restrict__ row_ptr, int n) {
    __shared__ int red[SCAN_BLK];
    __shared__ int s[SCAN_BLK];
    int acc = 0;
    for (int k = threadIdx.x; k < blockIdx.x; k += SCAN_BLK) acc += partials[k];
    red[threadIdx.x] = acc;
    __syncthreads();
    for (int off = SCAN_BLK / 2; off > 0; off >>= 1) {
        if (threadIdx.x < off) red[threadIdx.x] += red[threadIdx.x + off];
        __syncthreads();
    }
    int i = blockIdx.x * SCAN_BLK + threadIdx.x;
    int v = (i < n) ? deg[i] : 0;
    s[threadIdx.x] = v;
    __syncthreads();
    for (int off = 1; off < SCAN_BLK; off <<= 1) {
        int t = (threadIdx.x >= off) ? s[threadIdx.x - off] : 0;
        __syncthreads();
        s[threadIdx.x] += t;
        __syncthreads();
    }
    if (i < n) row_ptr[i] = red[0] + s[threadIdx.x] - v;
}

// ---- pass B: placement via LDS cursors (1 random store/edge) + outdeg/prescale tail ----
__global__ void place_kernel(const int* __restrict__ src, const int* __restrict__ dst,
                             const unsigned short* __restrict__ pcnt,
                             const int* __restrict__ row_ptr, int* __restrict__ csr_src,
                             const unsigned char* __restrict__ pcnt8,
                             const float* __restrict__ x,
                             float* __restrict__ inv_out, float* __restrict__ xs) {
    __shared__ int cur[RANGE_N];
    int c = blockIdx.x >> 3;
    int r = blockIdx.x & 7;
    int lo = r * RANGE_N;
    const unsigned short* p = pcnt + (size_t)c * N_NODES + lo;
    for (int k = threadIdx.x; k < RANGE_N; k += blockDim.x)
        cur[k] = row_ptr[lo + k] + (int)p[k];   // absolute base cursor
    __syncthreads();
    const int4* d4 = (const int4*)(dst + c * CHUNK_E);
    const int4* s4 = (const int4*)(src + c * CHUNK_E);
    for (int k = threadIdx.x; k < CHUNK_E / 4; k += blockDim.x) {
        int4 dv = d4[k];
        int d0 = dv.x - lo, d1 = dv.y - lo, d2 = dv.z - lo, d3 = dv.w - lo;
        bool n0 = (unsigned)d0 < RANGE_N, n1 = (unsigned)d1 < RANGE_N;
        bool n2 = (unsigned)d2 < RANGE_N, n3 = (unsigned)d3 < RANGE_N;
        if (n0 | n1 | n2 | n3) {   // skip src fetch when whole quad out of range
            int4 sv = s4[k];
            if (n0) csr_src[atomicAdd(&cur[d0], 1)] = sv.x;
            if (n1) csr_src[atomicAdd(&cur[d1], 1)] = sv.y;
            if (n2) csr_src[atomicAdd(&cur[d2], 1)] = sv.z;
            if (n3) csr_src[atomicAdd(&cur[d3], 1)] = sv.w;
        }
    }
    // ---- tail: out-degree sum + inv_out + prescale (depends only on hist's pcnt8) ----
    int i = blockIdx.x * blockDim.x + threadIdx.x;
    if (i < N_NODES) {
        int sd = 0;
#pragma unroll
        for (int cc = 0; cc < NCHUNK; cc++) sd += pcnt8[(size_t)cc * N_NODES + i];
        float io = 1.0f / sqrtf(fmaxf((float)sd, 1.0f));
        inv_out[i] = io;
        const float4* x4 = (const float4*)x;
        float4 a = x4[i * 2], b = x4[i * 2 + 1];
        a.x *= io; a.y *= io; a.z *= io; a.w *= io;
        b.x *= io; b.y *= io; b.z *= io; b.w *= io;
        float4* xs4 = (float4*)xs;
        xs4[i * 2] = a;
        xs4[i * 2 + 1] = b;
    }
}

// ---------------- layer 1 fused: gather d=8 (float4 x2 lanes) + @W1+b1, relu, *inv_out ----
__global__ __launch_bounds__(256) void
layer1_kernel(const float* __restrict__ xs, const int* __restrict__ row_ptr,
              const int* __restrict__ cnt_in, const int* __restrict__ csr_src,
              const float* __restrict__ inv_in, const float* __restrict__ inv_out,
              const float* __restrict__ W1, const float* __restrict__ b1,
              float* __restrict__ hout) {
    __shared__ float sW[8 * 16];
    __shared__ float sb[16];
    __shared__ float tile[128 * 8];
    if (threadIdx.x < 128) sW[threadIdx.x] = W1[threadIdx.x];
    if (threadIdx.x < 16) sb[threadIdx.x] = b1[threadIdx.x];
    int ii = threadIdx.x >> 1, f = threadIdx.x & 1;   // 2 lanes/node, float4 each
    int i = blockIdx.x * 128 + ii;
    const float4* xs4 = (const float4*)xs;
    float4 s = {0.f, 0.f, 0.f, 0.f};
    if (i < N_NODES) {
        int start = row_ptr[i], deg = cnt_in[i];
        int k = 0;
        for (; k + 7 < deg; k += 8) {   // 8 float4 loads in flight
            int e0 = csr_src[start + k],     e1 = csr_src[start + k + 1];
            int e2 = csr_src[start + k + 2], e3 = csr_src[start + k + 3];
            int e4 = csr_src[start + k + 4], e5 = csr_src[start + k + 5];
            int e6 = csr_src[start + k + 6], e7 = csr_src[start + k + 7];
            float4 v0 = xs4[e0 * 2 + f], v1 = xs4[e1 * 2 + f];
            float4 v2 = xs4[e2 * 2 + f], v3 = xs4[e3 * 2 + f];
            float4 v4 = xs4[e4 * 2 + f], v5 = xs4[e5 * 2 + f];
            float4 v6 = xs4[e6 * 2 + f], v7 = xs4[e7 * 2 + f];
            s.x += v0.x + v1.x + v2.x + v3.x + v4.x + v5.x + v6.x + v7.x;
            s.y += v0.y + v1.y + v2.y + v3.y + v4.y + v5.y + v6.y + v7.y;
            s.z += v0.z + v1.z + v2.z + v3.z + v4.z + v5.z + v6.z + v7.z;
            s.w += v0.w + v1.w + v2.w + v3.w + v4.w + v5.w + v6.w + v7.w;
        }
        for (; k < deg; k++) {
            float4 v = xs4[csr_src[start + k] * 2 + f];
            s.x += v.x; s.y += v.y; s.z += v.z; s.w += v.w;
        }
        float inv = inv_in[i];
        s.x *= inv; s.y *= inv; s.z *= inv; s.w *= inv;
    }
    ((float4*)tile)[ii * 2 + f] = s;
    __syncthreads();
#pragma unroll
    for (int rep = 0; rep < 8; rep++) {   // 128 nodes x 16 outputs
        int idx = threadIdx.x + rep * 256;
        int i2 = idx >> 4, j = idx & 15;
        int gi = blockIdx.x * 128 + i2;
        if (gi < N_NODES) {
            float o = sb[j];
#pragma unroll
            for (int k2 = 0; k2 < 8; k2++) o += tile[i2 * 8 + k2] * sW[k2 * 16 + j];
            hout[gi * 16 + j] = fmaxf(o, 0.0f) * inv_out[gi];
        }
    }
}

// ------- layer 2 fused: gather d=16 (float4 x4 lanes) + relu((.)@W2+b2)@W3, *inv_out ----
// Output stride 10 (p buffer = 4.0 MB: per-XCD L2 resident).
__global__ __launch_bounds__(256) void
layer2_kernel(const float* __restrict__ h, const int* __restrict__ row_ptr,
              const int* __restrict__ cnt_in, const int* __restrict__ csr_src,
              const float* __restrict__ inv_in, const float* __restrict__ inv_out,
              const float* __restrict__ W2, const float* __restrict__ b2,
              const float* __restrict__ W3, float* __restrict__ pout) {
    __shared__ float sW2[16 * 32];
    __shared__ float sb2[32];
    __shared__ float sW3[32 * 10];
    __shared__ float tile[64 * 16];
    __shared__ float otile[64 * 33];   // +1 pad: phase3 reads stride-32 across nodes
    for (int k = threadIdx.x; k < 512; k += 256) sW2[k] = W2[k];
    if (threadIdx.x < 32) sb2[threadIdx.x] = b2[threadIdx.x];
    for (int k = threadIdx.x; k < 320; k += 256) sW3[k] = W3[k];
    int ii = threadIdx.x >> 2, f = threadIdx.x & 3;   // 4 lanes/node, float4 each
    int i = blockIdx.x * 64 + ii;
    const float4* h4 = (const float4*)h;
    float4 s = {0.f, 0.f, 0.f, 0.f};
    if (i < N_NODES) {
        int start = row_ptr[i], deg = cnt_in[i];
        int k = 0;
        for (; k + 7 < deg; k += 8) {
            int e0 = csr_src[start + k],     e1 = csr_src[start + k + 1];
            int e2 = csr_src[start + k + 2], e3 = csr_src[start + k + 3];
            int e4 = csr_src[start + k + 4], e5 = csr_src[start + k + 5];
            int e6 = csr_src[start + k + 6], e7 = csr_src[start + k + 7];
            float4 v0 = h4[e0 * 4 + f], v1 = h4[e1 * 4 + f];
            float4 v2 = h4[e2 * 4 + f], v3 = h4[e3 * 4 + f];
            float4 v4 = h4[e4 * 4 + f], v5 = h4[e5 * 4 + f];
            float4 v6 = h4[e6 * 4 + f], v7 = h4[e7 * 4 + f];
            s.x += v0.x + v1.x + v2.x + v3.x + v4.x + v5.x + v6.x + v7.x;
            s.y += v0.y + v1.y + v2.y + v3.y + v4.y + v5.y + v6.y + v7.y;
            s.z += v0.z + v1.z + v2.z + v3.z + v4.z + v5.z + v6.z + v7.z;
            s.w += v0.w + v1.w + v2.w + v3.w + v4.w + v5.w + v6.w + v7.w;
        }
        for (; k < deg; k++) {
            float4 v = h4[csr_src[start + k] * 4 + f];
            s.x += v.x; s.y += v.y; s.z += v.z; s.w += v.w;
        }
        float inv = inv_in[i];
        s.x *= inv; s.y *= inv; s.z *= inv; s.w *= inv;
    }
    ((float4*)tile)[ii * 4 + f] = s;
    __syncthreads();
#pragma unroll
    for (int rep = 0; rep < 8; rep++) {   // 64 nodes x 32 hidden
        int idx = threadIdx.x + rep * 256;
        int i2 = idx >> 5, kk = idx & 31;
        if (blockIdx.x * 64 + i2 < N_NODES) {
            float o = sb2[kk];
#pragma unroll
            for (int m = 0; m < 16; m++) o += tile[i2 * 16 + m] * sW2[m * 32 + kk];
            otile[i2 * 33 + kk] = fmaxf(o, 0.0f);
        }
    }
    __syncthreads();
#pragma unroll
    for (int rep = 0; rep < 3; rep++) {   // 64 nodes x 10 outputs
        int idx = threadIdx.x + rep * 256;
        if (idx < 640) {
            int i2 = idx / 10, j = idx - i2 * 10;
            int gi = blockIdx.x * 64 + i2;
            if (gi < N_NODES) {
                float pv = 0.0f;
#pragma unroll
                for (int k2 = 0; k2 < 32; k2++) pv += otile[i2 * 33 + k2] * sW3[k2 * 10 + j];
                pout[gi * 10 + j] = pv * inv_out[gi];
            }
        }
    }
}

// ---- layer 3 (R7-proven, NO fence/ticket): gather d=10 scalar + *inv_in + b3
// ---- + LDS graph mean + sparse global-atomic flush ----
__global__ __launch_bounds__(1024) void
layer3_kernel(const float* __restrict__ p, const int* __restrict__ row_ptr,
              const int* __restrict__ cnt_in, const int* __restrict__ csr_src,
              const float* __restrict__ inv_in, const float* __restrict__ b3,
              const int* __restrict__ gid, float* __restrict__ gsum,
              float* __restrict__ gcnt, int n10) {
    __shared__ float sb3[10];
    __shared__ float lsum[N_GRAPHS * 10];
    __shared__ float lcnt[N_GRAPHS];
    if (threadIdx.x < 10) sb3[threadIdx.x] = b3[threadIdx.x];
    for (int k = threadIdx.x; k < N_GRAPHS * 10; k += 1024) lsum[k] = 0.0f;
    if (threadIdx.x < N_GRAPHS) lcnt[threadIdx.x] = 0.0f;
    __syncthreads();
    int t = blockIdx.x * 1024 + threadIdx.x;
    if (t < n10) {
        int i = t / 10, f = t - i * 10;
        int start = row_ptr[i], deg = cnt_in[i];
        float s = 0.0f;
        int k = 0;
        for (; k + 7 < deg; k += 8) {
            int e0 = csr_src[start + k],     e1 = csr_src[start + k + 1];
            int e2 = csr_src[start + k + 2], e3 = csr_src[start + k + 3];
            int e4 = csr_src[start + k + 4], e5 = csr_src[start + k + 5];
            int e6 = csr_src[start + k + 6], e7 = csr_src[start + k + 7];
            s += p[e0 * 10 + f]; s += p[e1 * 10 + f]; s += p[e2 * 10 + f]; s += p[e3 * 10 + f];
            s += p[e4 * 10 + f]; s += p[e5 * 10 + f]; s += p[e6 * 10 + f]; s += p[e7 * 10 + f];
        }
        for (; k < deg; k++) s += p[csr_src[start + k] * 10 + f];
        float o = s * inv_in[i] + sb3[f];
        int g = gid[i];
        atomicAdd(&lsum[g * 10 + f], o);
        if (f == 0) atomicAdd(&lcnt[g], 1.0f);
    }
    __syncthreads();
    for (int k = threadIdx.x; k < N_GRAPHS * 10; k += 1024) {
        float v = lsum[k];
        if (v != 0.0f) atomicAdd(&gsum[k], v);
    }
    if (threadIdx.x < N_GRAPHS) {
        float v = lcnt[threadIdx.x];
        if (v != 0.0f) atomicAdd(&gcnt[threadIdx.x], v);
    }
}

__global__ void finalize_kernel(const float* __restrict__ gsum, const float* __restrict__ gcnt,
                                float* __restrict__ out) {
    int t = blockIdx.x * blockDim.x + threadIdx.x;
    if (t < N_GRAPHS * 10) {
        int g = t / 10;
        out[t] = gsum[t] / fmaxf(gcnt[g], 1.0f);
    }
}

extern "C" void kernel_launch(void* const* d_in, const int* in_sizes, int n_in,
                              void* d_out, int out_size, void* d_ws, size_t ws_size,
                              hipStream_t stream) {
    const float* n_feat = (const float*)d_in[0];  // [N,8]
    const int*   src    = (const int*)d_in[1];    // [E]
    const int*   dst    = (const int*)d_in[2];    // [E]
    const int*   gid    = (const int*)d_in[3];    // [N]
    const float* W1     = (const float*)d_in[4];  // [8,16]
    const float* b1     = (const float*)d_in[5];
    const float* W2     = (const float*)d_in[6];  // [16,32]
    const float* b2     = (const float*)d_in[7];
    const float* W3     = (const float*)d_in[8];  // [32,10]
    const float* b3     = (const float*)d_in[9];
    float* out = (float*)d_out;

    // ---- workspace layout (~30.4 MB; >=32.4 MB proven available in R4) ----
    float* ws      = (float*)d_ws;
    float* inv_out = ws;
    float* inv_in  = ws + N_NODES;
    float* bufA    = ws + 2 * N_NODES;    // h16 (16N)
    float* bufB    = ws + 18 * N_NODES;   // xs (8N), later p10 (10N)
    float* gsum    = ws + 34 * N_NODES;
    float* gcnt    = gsum + N_GRAPHS * 10;
    int* ibase     = (int*)(gcnt + N_GRAPHS);
    int* cnt_in    = ibase;
    int* row_ptr   = ibase + N_NODES;
    int* spart     = ibase + 2 * N_NODES;
    int* csr_src   = ibase + 2 * N_NODES + 1024;
    unsigned short* pcnt = (unsigned short*)(csr_src + N_EDGES);
    unsigned int* pcnt8 = (unsigned int*)(pcnt + (size_t)NCHUNK * N_NODES);

    const int BIGBLK = 1024;
    const int NPARTS = (N_NODES + SCAN_BLK - 1) / SCAN_BLK;  // 391
    const int TGRID = NCHUNK * NRANGE;                        // 256

    // ---- atomic-free graph build (4 dispatches) ----
    hist_kernel<<<TGRID, BIGBLK, 0, stream>>>(dst, src, pcnt, pcnt8);
    chunkscanA_kernel<<<NPARTS, SCAN_BLK, 0, stream>>>(pcnt, cnt_in, inv_in, spart,
                                                       gsum, N_NODES);
    scanC_kernel<<<NPARTS, SCAN_BLK, 0, stream>>>(cnt_in, spart, row_ptr, N_NODES);
    place_kernel<<<TGRID, BIGBLK, 0, stream>>>(src, dst, pcnt, row_ptr, csr_src,
                                               (const unsigned char*)pcnt8, n_feat,
                                               inv_out, bufB);

    // ---- three fused layers + finalize (4 dispatches) ----
    layer1_kernel<<<(N_NODES + 127) / 128, 256, 0, stream>>>(
        bufB, row_ptr, cnt_in, csr_src, inv_in, inv_out, W1, b1, bufA);
    layer2_kernel<<<(N_NODES + 63) / 64, 256, 0, stream>>>(
        bufA, row_ptr, cnt_in, csr_src, inv_in, inv_out, W2, b2, W3, bufB);
    layer3_kernel<<<(N_NODES * 10 + BIGBLK - 1) / BIGBLK, BIGBLK, 0, stream>>>(
        bufB, row_ptr, cnt_in, csr_src, inv_in, b3, gid, gsum, gcnt, N_NODES * 10);
    finalize_kernel<<<1, 640, 0, stream>>>(gsum, gcnt, out);
}